// Round 1
// baseline (5122.885 us; speedup 1.0000x reference)
//
#include <hip/hip_runtime.h>

#define Hh 64
#define Tt 2048
#define Bb 256
#define Gg 192   // 3*H gate rows, PyTorch order: r, z, n

__device__ __forceinline__ float fast_sigmoid(float x) {
    return 1.0f / (1.0f + __expf(-x));
}
__device__ __forceinline__ float fast_tanh(float x) {
    // 1 - 2/(exp(2x)+1): saturates cleanly to +/-1, no inf/inf NaN
    float e = __expf(2.0f * x);
    return 1.0f - 2.0f / (e + 1.0f);
}

// IN_CHW: input layout 1 -> [B, H, T] (channel-first), 0 -> [B, T, H]
// OUT_CHW: same for output
template<int IN_CHW, int OUT_CHW>
__global__ __launch_bounds__(Gg)
void gru_scan(const float* __restrict__ in, float* __restrict__ out,
              const float* __restrict__ Wih, const float* __restrict__ Whh,
              const float* __restrict__ bih, const float* __restrict__ bhh)
{
    const int b = blockIdx.x;
    const int g = threadIdx.x;   // 0..191: gate row

    // Per-thread weight rows in registers (32 float4 = 128 VGPR)
    float4 wih[16], whh[16];
#pragma unroll
    for (int k = 0; k < 16; ++k) {
        wih[k] = ((const float4*)(Wih + (long)g * Hh))[k];
        whh[k] = ((const float4*)(Whh + (long)g * Hh))[k];
    }
    const float bi = bih[g];
    const float bh = bhh[g];

    __shared__ float xbuf[Hh];     // x_t
    __shared__ float hbuf[Hh];     // h_{t-1}
    __shared__ float srz[2 * Hh];  // pre-activation sums for r,z
    __shared__ float sxn[Hh];      // gx_n
    __shared__ float shn[Hh];      // gh_n

    const long ibase = (long)b * (Hh * Tt);  // both layouts have same per-b extent
    const long obase = (long)b * (Hh * Tt);

    if (g < Hh) {
        hbuf[g] = 0.0f;
        xbuf[g] = IN_CHW ? in[ibase + (long)g * Tt] : in[ibase + g];
    }
    __syncthreads();

#pragma unroll 1
    for (int t = 0; t < Tt; ++t) {
        // Prefetch x_{t+1} (wave 0 only); committed to LDS in the gate phase.
        float xn = 0.0f;
        if (g < Hh && (t + 1) < Tt) {
            xn = IN_CHW ? in[ibase + (long)g * Tt + (t + 1)]
                        : in[ibase + (long)(t + 1) * Hh + g];
        }

        // Dual dot products: ax = Wih[g,:]·x_t + bih[g], ah = Whh[g,:]·h + bhh[g]
        // 4 independent FMA chains to break dependency latency.
        float axA = bi, axB = 0.0f, ahA = bh, ahB = 0.0f;
#pragma unroll
        for (int k = 0; k < 16; ++k) {
            float4 xv = ((const float4*)xbuf)[k];  // uniform addr -> LDS broadcast
            float4 hv = ((const float4*)hbuf)[k];
            float4 wx = wih[k];
            float4 wh = whh[k];
            if (k & 1) {
                axB = fmaf(wx.x, xv.x, axB); axB = fmaf(wx.y, xv.y, axB);
                axB = fmaf(wx.z, xv.z, axB); axB = fmaf(wx.w, xv.w, axB);
                ahB = fmaf(wh.x, hv.x, ahB); ahB = fmaf(wh.y, hv.y, ahB);
                ahB = fmaf(wh.z, hv.z, ahB); ahB = fmaf(wh.w, hv.w, ahB);
            } else {
                axA = fmaf(wx.x, xv.x, axA); axA = fmaf(wx.y, xv.y, axA);
                axA = fmaf(wx.z, xv.z, axA); axA = fmaf(wx.w, xv.w, axA);
                ahA = fmaf(wh.x, hv.x, ahA); ahA = fmaf(wh.y, hv.y, ahA);
                ahA = fmaf(wh.z, hv.z, ahA); ahA = fmaf(wh.w, hv.w, ahA);
            }
        }
        const float ax = axA + axB;
        const float ah = ahA + ahB;

        if (g < 2 * Hh) {
            srz[g] = ax + ah;                 // r (g<64) and z (64<=g<128)
        } else {
            sxn[g - 2 * Hh] = ax;             // n-gate input part
            shn[g - 2 * Hh] = ah;             // n-gate hidden part
        }
        __syncthreads();

        if (g < Hh) {
            const float r = fast_sigmoid(srz[g]);
            const float z = fast_sigmoid(srz[Hh + g]);
            const float n = fast_tanh(fmaf(r, shn[g], sxn[g]));
            const float hold = hbuf[g];
            const float hnew = fmaf(z, hold - n, n);   // (1-z)*n + z*h
            hbuf[g] = hnew;
            xbuf[g] = xn;                               // commit prefetched x_{t+1}
            if (OUT_CHW) out[obase + (long)g * Tt + t] = hnew;
            else         out[obase + (long)t * Hh + g] = hnew;
        }
        __syncthreads();
    }
}

extern "C" void kernel_launch(void* const* d_in, const int* in_sizes, int n_in,
                              void* d_out, int out_size, void* d_ws, size_t ws_size,
                              hipStream_t stream) {
    const float* x   = (const float*)d_in[0];   // [B, H, T]
    const float* Wih = (const float*)d_in[1];   // [3, 192, 64]
    const float* Whh = (const float*)d_in[2];   // [3, 192, 64]
    const float* bih = (const float*)d_in[3];   // [3, 192]
    const float* bhh = (const float*)d_in[4];   // [3, 192]
    float* out = (float*)d_out;                 // [B, H, T]
    float* ws  = (float*)d_ws;                  // one [B, T, H] fp32 buffer = 128 MB

    // Layer 0: [B,H,T] -> ws [B,T,H]
    gru_scan<1, 0><<<Bb, Gg, 0, stream>>>(x, ws,
        Wih + 0 * Gg * Hh, Whh + 0 * Gg * Hh, bih + 0 * Gg, bhh + 0 * Gg);
    // Layer 1: ws -> ws in-place (read t+1 happens before write t per thread)
    gru_scan<0, 0><<<Bb, Gg, 0, stream>>>(ws, ws,
        Wih + 1 * Gg * Hh, Whh + 1 * Gg * Hh, bih + 1 * Gg, bhh + 1 * Gg);
    // Layer 2: ws -> out [B,H,T]
    gru_scan<0, 1><<<Bb, Gg, 0, stream>>>(ws, out,
        Wih + 2 * Gg * Hh, Whh + 2 * Gg * Hh, bih + 2 * Gg, bhh + 2 * Gg);
}

// Round 3
// 3322.882 us; speedup vs baseline: 1.5417x; 1.5417x over previous
//
#include <hip/hip_runtime.h>

#define Hh 64
#define Tt 2048
#define Bb 256
#define NL 3

__device__ __forceinline__ float fast_sigmoid(float x) {
    return 1.0f / (1.0f + __expf(-x));
}
__device__ __forceinline__ float fast_tanh(float x) {
    float e = __expf(2.0f * x);
    return 1.0f - 2.0f / (e + 1.0f);
}

__device__ __forceinline__ float fma4(float acc, const float4& a, const float4& b) {
    acc = fmaf(a.x, b.x, acc);
    acc = fmaf(a.y, b.y, acc);
    acc = fmaf(a.z, b.z, acc);
    acc = fmaf(a.w, b.w, acc);
    return acc;
}

// One block per batch element. Wave l (= threadIdx.x>>6) runs GRU layer l,
// software-pipelined with skew 1: at phase p, wave l processes t = p - l.
// Lane i owns gate rows {i, 64+i, 128+i}; computes h_new[i] fully locally.
// h vectors are exchanged via double-buffered LDS broadcast, ONE barrier/phase.
__global__ __launch_bounds__(192, 1)
void gru_pipe(const float* __restrict__ in, float* __restrict__ out,
              const float* __restrict__ Wih, const float* __restrict__ Whh,
              const float* __restrict__ bih, const float* __restrict__ bhh)
{
    const int b   = blockIdx.x;
    const int tid = threadIdx.x;
    const int l   = tid >> 6;    // wave index = layer
    const int i   = tid & 63;    // lane = hidden unit

    // ---- weights for this lane's 3 gate rows, in registers (384 VGPR) ----
    const float* WihL = Wih + (long)l * 192 * 64;
    const float* WhhL = Whh + (long)l * 192 * 64;
    float4 wxr[16], wxz[16], wxn[16], whr[16], whz[16], whn[16];
#pragma unroll
    for (int k = 0; k < 16; ++k) {
        wxr[k] = ((const float4*)(WihL + (long)(i)       * 64))[k];
        wxz[k] = ((const float4*)(WihL + (long)(64 + i)  * 64))[k];
        wxn[k] = ((const float4*)(WihL + (long)(128 + i) * 64))[k];
        whr[k] = ((const float4*)(WhhL + (long)(i)       * 64))[k];
        whz[k] = ((const float4*)(WhhL + (long)(64 + i)  * 64))[k];
        whn[k] = ((const float4*)(WhhL + (long)(128 + i) * 64))[k];
    }
    const float bxr = bih[l*192 + i];
    const float bxz = bih[l*192 + 64 + i];
    const float bxn = bih[l*192 + 128 + i];
    const float bhr = bhh[l*192 + i];
    const float bhz = bhh[l*192 + 64 + i];
    const float bhn = bhh[l*192 + 128 + i];

    __shared__ float hbuf[NL][2][Hh];   // per-layer h, double-buffered by phase parity
    __shared__ float xbuf[2][Hh];       // layer-0 input x_t, double-buffered

    const long ib = (long)b * Hh * Tt;  // [B,H,T] base for this batch element

    // ---- init ----
    hbuf[l][0][i] = 0.0f;
    hbuf[l][1][i] = 0.0f;
    float hprev = 0.0f;                 // this lane's own h (scalar)
    float xcur = 0.0f;                  // holds x_{p+1} during phase p (wave 0)
    if (l == 0) {
        xbuf[0][i] = in[ib + (long)i * Tt + 0];   // x_{t=0}
        xcur       = in[ib + (long)i * Tt + 1];   // x_{t=1}
    }
    __syncthreads();

    for (int p = 0; p < Tt + NL - 1; ++p) {
        const int rd = p & 1;
        const int wr = rd ^ 1;
        const int t  = p - l;

        // Wave 0: commit x_{p+1} to LDS for next phase, prefetch x_{p+2}.
        // Global load issued at phase TOP so the pre-barrier vmcnt drain
        // hides under the ~800 cycles of FMA issue below.
        float xnext = 0.0f;
        if (l == 0) {
            if (p + 1 < Tt) xbuf[wr][i] = xcur;
            if (p + 2 < Tt) xnext = in[ib + (long)i * Tt + (p + 2)];
        }

        if (t >= 0 && t < Tt) {
            const float4* xs4 = (const float4*)((l == 0) ? xbuf[rd]
                                                         : hbuf[l - 1][rd]);
            const float4* hs4 = (const float4*)hbuf[l][rd];

            float axr = bxr, axz = bxz, axn = bxn;
            float ahr = bhr, ahz = bhz, ahn = bhn;
#pragma unroll
            for (int k = 0; k < 16; ++k) {
                const float4 xv = xs4[k];   // uniform addr -> LDS broadcast
                const float4 hv = hs4[k];
                axr = fma4(axr, wxr[k], xv);
                axz = fma4(axz, wxz[k], xv);
                axn = fma4(axn, wxn[k], xv);
                ahr = fma4(ahr, whr[k], hv);
                ahz = fma4(ahz, whz[k], hv);
                ahn = fma4(ahn, whn[k], hv);
            }

            const float r = fast_sigmoid(axr + ahr);
            const float z = fast_sigmoid(axz + ahz);
            const float n = fast_tanh(fmaf(r, ahn, axn));
            const float hnew = fmaf(z, hprev - n, n);   // (1-z)*n + z*h
            hprev = hnew;
            hbuf[l][wr][i] = hnew;
            if (l == NL - 1) out[ib + (long)i * Tt + t] = hnew;
        }

        if (l == 0) xcur = xnext;
        __syncthreads();
    }
}

extern "C" void kernel_launch(void* const* d_in, const int* in_sizes, int n_in,
                              void* d_out, int out_size, void* d_ws, size_t ws_size,
                              hipStream_t stream) {
    const float* x   = (const float*)d_in[0];   // [B, H, T]
    const float* Wih = (const float*)d_in[1];   // [3, 192, 64]
    const float* Whh = (const float*)d_in[2];   // [3, 192, 64]
    const float* bih = (const float*)d_in[3];   // [3, 192]
    const float* bhh = (const float*)d_in[4];   // [3, 192]
    float* out = (float*)d_out;                 // [B, H, T]

    gru_pipe<<<Bb, 192, 0, stream>>>(x, out, Wih, Whh, bih, bhh);
}